// Round 6
// baseline (2572.408 us; speedup 1.0000x reference)
//
#include <hip/hip_runtime.h>

typedef unsigned int u32;

#define N_TOK 65536
#define DIM 256
#define NE 4096
#define TM 128
#define TN 64
#define TK 64
#define LDX 68  // x-tile leading dim (floats): 16B-aligned rows, breaks pow2 bank stride
#define LDE 68  // e-tile leading dim

__device__ __align__(16) float g_enorm[NE];     // np-exact sum(embed^2, axis=0)
__device__ __align__(16) float g_xnorm[N_TOK];  // np-exact sum(x^2, axis=1)
__device__ float g_diffarr[64];                 // diff partial bins

__device__ __forceinline__ float sqr_rn(float v) { return __fmul_rn(v, v); }

// NumPy pairwise_sum for a 128-block of squares: 8 accumulators, 8-way unrolled,
// combine ((r0+r1)+(r2+r3)) + ((r4+r5)+(r6+r7)). Non-fused (matches temp-array sum).
__device__ float np_sum128_sq(const float* __restrict__ a) {
    float r[8];
#pragma unroll
    for (int j = 0; j < 8; ++j) r[j] = sqr_rn(a[j]);
    for (int i = 8; i < 128; i += 8)
#pragma unroll
        for (int j = 0; j < 8; ++j) r[j] = __fadd_rn(r[j], sqr_rn(a[i + j]));
    return __fadd_rn(__fadd_rn(__fadd_rn(r[0], r[1]), __fadd_rn(r[2], r[3])),
                     __fadd_rn(__fadd_rn(r[4], r[5]), __fadd_rn(r[6], r[7])));
}

// ---------------- K1a: x row norms, np-pairwise bit-exact (n=256 -> 128+128) --
__global__ void k_xnorm(const float* __restrict__ x) {
    const int n = blockIdx.x * 256 + threadIdx.x;
    const float* row = x + (size_t)n * DIM;
    g_xnorm[n] = __fadd_rn(np_sum128_sq(row), np_sum128_sq(row + 128));
    if (blockIdx.x == 0 && threadIdx.x < 64) g_diffarr[threadIdx.x] = 0.f;
}

// ---------------- K1b: embed col norms, np axis-0 sequential bit-exact -------
__global__ void k_enorm(const float* __restrict__ embed) {
    const int e = blockIdx.x * 256 + threadIdx.x;  // coalesced over e
    float s = sqr_rn(embed[e]);
    for (int d = 1; d < DIM; ++d) s = __fadd_rn(s, sqr_rn(embed[(size_t)d * NE + e]));
    g_enorm[e] = s;
}

// ---------------- K2: distance GEMM + argmin, bit-matching np float32 --------
// dot: single sequential fp32 FMA chain over k=0..255 ascending (== BLAS microkernel).
// score = (xnorm - 2*dot) + enorm, each op fp32-rounded (np left-to-right).
// argmax(-dist) == first occurrence of min -> strict < with ascending-e scan.
__global__ __launch_bounds__(256, 2)
void k_argmin(const float* __restrict__ x, const float* __restrict__ embed,
              float* __restrict__ out_ind) {
    __shared__ float xs[TM * LDX];  // 128 x 64 (+pad) = 34.8 KB
    __shared__ float es[TK * LDE];  // 64 x 64 (+pad)  = 17.4 KB
    const int tid = threadIdx.x;
    const int tx = tid & 15;        // 16 code-lanes x 4 codes
    const int ty = tid >> 4;        // token rows r = i*16 + ty
    const int n0 = blockIdx.x * TM;

    float xn[8];
#pragma unroll
    for (int i = 0; i < 8; i++) xn[i] = g_xnorm[n0 + i * 16 + ty];

    float best[8];
    int bidx[8];
#pragma unroll
    for (int i = 0; i < 8; i++) { best[i] = 3.0e38f; bidx[i] = 0; }

    for (int et = 0; et < NE / TN; ++et) {
        const int e0 = et * TN;
        float acc[8][4];
#pragma unroll
        for (int i = 0; i < 8; i++)
#pragma unroll
            for (int j = 0; j < 4; j++) acc[i][j] = 0.f;

        for (int kt = 0; kt < DIM / TK; ++kt) {
            const int k0 = kt * TK;
            __syncthreads();
#pragma unroll
            for (int i = 0; i < 8; i++) {  // x tile 128x64: 2048 float4
                int f = tid + i * 256;
                int r = f >> 4, c4 = f & 15;
                *(float4*)&xs[r * LDX + c4 * 4] =
                    *(const float4*)(x + (size_t)(n0 + r) * DIM + k0 + c4 * 4);
            }
#pragma unroll
            for (int i = 0; i < 4; i++) {  // embed tile 64x64: 1024 float4
                int f = tid + i * 256;
                int r = f >> 4, c4 = f & 15;
                *(float4*)&es[r * LDE + c4 * 4] =
                    *(const float4*)(embed + (size_t)(k0 + r) * NE + e0 + c4 * 4);
            }
            __syncthreads();
#pragma unroll 4
            for (int g = 0; g < TK / 4; ++g) {
                const int k = g * 4;
                float ev[4][4];
#pragma unroll
                for (int kk = 0; kk < 4; kk++) {
                    float4 t = *(const float4*)&es[(k + kk) * LDE + tx * 4];
                    ev[kk][0] = t.x; ev[kk][1] = t.y; ev[kk][2] = t.z; ev[kk][3] = t.w;
                }
#pragma unroll
                for (int i = 0; i < 8; i++) {
                    float4 xt = *(const float4*)&xs[(i * 16 + ty) * LDX + k];
                    float xk[4] = {xt.x, xt.y, xt.z, xt.w};
#pragma unroll
                    for (int j = 0; j < 4; j++)
#pragma unroll
                        for (int kk = 0; kk < 4; kk++)   // k ascending: one FMA chain
                            acc[i][j] = fmaf(xk[kk], ev[kk][j], acc[i][j]);
                }
            }
        }
        const float4 en4 = *(const float4*)&g_enorm[e0 + tx * 4];
        const float enj[4] = {en4.x, en4.y, en4.z, en4.w};
#pragma unroll
        for (int i = 0; i < 8; i++) {
#pragma unroll
            for (int j = 0; j < 4; j++) {
                // np: ((xnorm - 2*mm) + enorm), each fp32-rounded
                float v = __fadd_rn(__fsub_rn(xn[i], __fmul_rn(2.0f, acc[i][j])), enj[j]);
                int e = e0 + tx * 4 + j;
                if (v < best[i]) { best[i] = v; bidx[i] = e; }
            }
        }
    }
    // reduce across the 16 tx lanes per token row; ties -> smaller index (np first-min)
#pragma unroll
    for (int i = 0; i < 8; i++) {
        float b = best[i];
        int bi = bidx[i];
#pragma unroll
        for (int m = 1; m < 16; m <<= 1) {
            float ob = __shfl_xor(b, m, 64);
            int oi = __shfl_xor(bi, m, 64);
            if (ob < b || (ob == b && oi < bi)) { b = ob; bi = oi; }
        }
        if (tx == 0) out_ind[n0 + i * 16 + ty] = (float)bi;
    }
}

// ---------------- K3: gather quantize (fp32) + diff partials -----------------
__global__ void k_gather(const float* __restrict__ x, const float* __restrict__ embed,
                         const float* __restrict__ out_ind, float* __restrict__ outq) {
    const int n = blockIdx.x;
    const int d = threadIdx.x;
    int e = (int)out_ind[n];
    e = e < 0 ? 0 : (e > NE - 1 ? NE - 1 : e);  // OOB-proof
    const float v = embed[(size_t)d * NE + e];
    outq[(size_t)n * DIM + d] = v;
    float sq = v - x[(size_t)n * DIM + d];
    sq *= sq;
#pragma unroll
    for (int m = 1; m < 64; m <<= 1) sq += __shfl_xor(sq, m, 64);
    __shared__ float wsum[4];
    if ((d & 63) == 0) wsum[d >> 6] = sq;
    __syncthreads();
    if (d == 0) atomicAdd(&g_diffarr[n & 63], wsum[0] + wsum[1] + wsum[2] + wsum[3]);
}

// ---------------- K4: publish diff -------------------------------------------
__global__ void k_finish(float* __restrict__ out_diff) {
    float t = 0.f;
    for (int w = 0; w < 64; ++w) t += g_diffarr[w];
    if (threadIdx.x == 0) *out_diff = t * (1.0f / 16777216.0f);
}

extern "C" void kernel_launch(void* const* d_in, const int* in_sizes, int n_in,
                              void* d_out, int out_size, void* d_ws, size_t ws_size,
                              hipStream_t stream) {
    // fp32 in / fp32 out (R5: outputs 0,1 passed). Output 2 must bit-match the np
    // float32 reference: sequential-FMA sgemm chain + np pairwise/sequential norms.
    const float* x = (const float*)d_in[0];      // [65536, 256]
    const float* embed = (const float*)d_in[1];  // [256, 4096]
    float* outq = (float*)d_out;                 // quantize: [0, 16777216)
    float* out_diff = outq + 16777216;           // diff scalar
    float* out_ind = outq + 16777217;            // embed_ind (float-coded): 65536

    hipLaunchKernelGGL(k_xnorm, dim3(N_TOK / 256), dim3(256), 0, stream, x);
    hipLaunchKernelGGL(k_enorm, dim3(NE / 256), dim3(256), 0, stream, embed);
    hipLaunchKernelGGL(k_argmin, dim3(N_TOK / TM), dim3(256), 0, stream, x, embed, out_ind);
    hipLaunchKernelGGL(k_gather, dim3(N_TOK), dim3(256), 0, stream, x, embed, out_ind, outq);
    hipLaunchKernelGGL(k_finish, dim3(1), dim3(64), 0, stream, out_diff);
}